// Round 6
// baseline (1270.688 us; speedup 1.0000x reference)
//
#include <hip/hip_runtime.h>
#include <math.h>

#define NUM_K 4096
#define DIM   256
#define TLEN  1024
#define DT    (DIM * TLEN)     // 262144, per-batch z stride
#define CAP   4096             // block candidate capacity (warm-started: E ~400)

typedef short bf16x8 __attribute__((ext_vector_type(8)));   // 8 bf16 in 4 VGPRs
typedef float f32x4  __attribute__((ext_vector_type(4)));

// float -> bf16, round-to-nearest-even (bit trick; inputs finite)
static __device__ __forceinline__ unsigned short f2bf(float x) {
  unsigned u = __float_as_uint(x);
  u += 0x7fffu + ((u >> 16) & 1u);
  return (unsigned short)(u >> 16);
}

static __device__ __forceinline__ f32x4 mfma16(bf16x8 a, bf16x8 b, f32x4 c) {
  return __builtin_amdgcn_mfma_f32_16x16x32_bf16(a, b, c, 0, 0, 0);
}

// async global->LDS DMA, 16B/lane: LDS dest = wave-uniform base + lane*16,
// global src = per-lane address. Zero VGPR cost (the fix for R3-R5's reg spills).
static __device__ __forceinline__ void gl_lds16(const void* g, void* l) {
  __builtin_amdgcn_global_load_lds(
      (const __attribute__((address_space(1))) unsigned int*)g,
      (__attribute__((address_space(3))) unsigned int*)l, 16, 0, 0);
}

// Max-reduce across each DPP row of 16 lanes (4 in-row permutations cover all 16).
// old=src: disabled-lane cases degrade to identity => reduce over a SUBSET => can
// only LOWER the running max => looser threshold => still-correct superset.
static __device__ __forceinline__ float dppmax16(float v) {
  int x = __float_as_int(v); int y;
  y = __builtin_amdgcn_update_dpp(x, x, 0xB1, 0xF, 0xF, false);   // quad_perm(1,0,3,2)
  v = fmaxf(v, __int_as_float(y)); x = __float_as_int(v);
  y = __builtin_amdgcn_update_dpp(x, x, 0x4E, 0xF, 0xF, false);   // quad_perm(2,3,0,1)
  v = fmaxf(v, __int_as_float(y)); x = __float_as_int(v);
  y = __builtin_amdgcn_update_dpp(x, x, 0x141, 0xF, 0xF, false);  // row_half_mirror
  v = fmaxf(v, __int_as_float(y)); x = __float_as_int(v);
  y = __builtin_amdgcn_update_dpp(x, x, 0x140, 0xF, 0xF, false);  // row_mirror
  v = fmaxf(v, __int_as_float(y));
  return v;
}

// ---------------- K1a: per-code norms m_c = max(||w_c||, 1e-6), numpy-bitwise ----------------
__global__ __launch_bounds__(256) void wnorm_kernel(const float* __restrict__ w,
                                                    float* __restrict__ wnorms) {
  const int k = blockIdx.x * 256 + threadIdx.x;
  const float* row = w + (size_t)k * DIM;
  float p[2];
#pragma unroll
  for (int blk = 0; blk < 2; ++blk) {
    const float* b = row + blk * 128;
    float r[8];
#pragma unroll
    for (int j = 0; j < 8; ++j) r[j] = __fmul_rn(b[j], b[j]);
    for (int i = 8; i < 128; i += 8) {
#pragma unroll
      for (int j = 0; j < 8; ++j) r[j] = __fadd_rn(r[j], __fmul_rn(b[i + j], b[i + j]));
    }
    p[blk] = __fadd_rn(__fadd_rn(__fadd_rn(r[0], r[1]), __fadd_rn(r[2], r[3])),
                       __fadd_rn(__fadd_rn(r[4], r[5]), __fadd_rn(r[6], r[7])));
  }
  wnorms[k] = fmaxf(__fsqrt_rn(__fadd_rn(p[0], p[1])), 1e-6f);
}

// ---------------- K1b: fp32 normalized codebook wnf32[k][d] = fdiv(w, m_k) ----------------
__global__ __launch_bounds__(256) void wnf32_kernel(const float* __restrict__ w,
                                                    const float* __restrict__ wnorms,
                                                    float* __restrict__ wnf) {
  const int idx = blockIdx.x * 256 + threadIdx.x;   // 0..262143 (float4 units)
  const float m = wnorms[idx >> 6];
  const float4 v = *reinterpret_cast<const float4*>(w + (size_t)idx * 4);
  float4 o;
  o.x = __fdiv_rn(v.x, m); o.y = __fdiv_rn(v.y, m);
  o.z = __fdiv_rn(v.z, m); o.w = __fdiv_rn(v.w, m);
  *reinterpret_cast<float4*>(wnf + (size_t)idx * 4) = o;
}

// ---------------- K1c: bf16 B-fragment image of wn ----------------
// fragid = chunk*32 + kb*4 + jg; each fragment 1 KB = 64 lanes x 16 B:
// B[k = (lane>>4)*8 + u][col = jg*16 + (lane&15)] for mfma 16x16x32 bf16.
// Phase view: 16 KB half-chunk ph = chunk*2 + h holds kb in [4h, 4h+4).
__global__ __launch_bounds__(256) void wfrag_kernel(const float* __restrict__ wnf,
                                                    unsigned short* __restrict__ img) {
  const int t = blockIdx.x * 256 + threadIdx.x;
  const int lane = t & 63;
  const int fragid = t >> 6;                           // 0..2047
  const int jg = fragid & 3;
  const int kb = (fragid >> 2) & 7;
  const int chunk = fragid >> 5;
  const int c  = (chunk << 6) + (jg << 4) + (lane & 15);
  const int d0 = (kb << 5) + ((lane >> 4) << 3);
  const float* src = wnf + (size_t)c * DIM + d0;
  union { bf16x8 v; unsigned short u[8]; } o;
#pragma unroll
  for (int u = 0; u < 8; ++u) o.u[u] = f2bf(src[u]);
  *reinterpret_cast<bf16x8*>(img + (size_t)fragid * 512 + lane * 8) = o.v;
}

// ---------------- K2: main fused kernel ----------------
// R6: LDS-staged B via async global_load_lds (m97 pattern) — registers hold only
// afr+acc (~120 VGPR, no spill). 512 threads/block, 128 tokens, 512 blocks (=2/CU
// co-resident). Loop of 128 phases (16KB half-chunks), double-buffered, ONE barrier
// per phase (the __syncthreads pre-barrier drain completes each wave's own DMA).
// Running max WARM-STARTED on chunk 63 (collect-free) to kill the early-chunk
// candidate flood. Verdict math unchanged: window 0.02*m_t (2.56x certified bf16
// error bound; superset argument: threshold_t = runmax_t - window <= final_max -
// window, and approx(c*) >= final_max - 2eps, window > 2eps), exact numpy fp32
// seq-FMA rescore, atomicMax64 packed-key select (max score, lowest code on ties).
__global__ __launch_bounds__(512, 4) void vq_main_kernel(
    const float* __restrict__ z, const float* __restrict__ weight,
    const unsigned short* __restrict__ wimg, const float* __restrict__ wnf32,
    float* __restrict__ znT, float* __restrict__ out_codes,
    float* __restrict__ counts, float* __restrict__ loss_accum) {
  __shared__ __attribute__((aligned(16))) char bstage[2][16384];
  __shared__ float pp[2][128];
  __shared__ float tnorm[128];
  __shared__ int   fidx[128];
  __shared__ int   clist[CAP];
  __shared__ int   ccount;
  __shared__ unsigned long long tokbest[128];

  const int tid  = threadIdx.x;
  const int lane = tid & 63;
  const int wv   = tid >> 6;          // wave 0..7
  const int wr   = wv >> 1;           // token quarter (32 tokens)
  const int wc   = wv & 1;            // code half within a 64-code chunk
  const int blk  = blockIdx.x;        // 0..511
  const float* zb = z + (size_t)(blk >> 3) * DT + ((blk & 7) << 7);
  const int gtok0 = blk << 7;

  // ---- per-token norms, numpy-bitwise pairwise scheme (256 threads: tok x 128-block) ----
  if (tid < 256) {
    const int tok = tid & 127, b2 = tid >> 7;
    const float* zc = zb + tok;
    float r[8];
#pragma unroll
    for (int j = 0; j < 8; ++j) {
      const float v = zc[(size_t)(b2 * 128 + j) * TLEN];
      r[j] = __fmul_rn(v, v);
    }
    for (int i = 8; i < 128; i += 8) {
#pragma unroll
      for (int j = 0; j < 8; ++j) {
        const float v = zc[(size_t)(b2 * 128 + i + j) * TLEN];
        r[j] = __fadd_rn(r[j], __fmul_rn(v, v));
      }
    }
    pp[b2][tok] = __fadd_rn(__fadd_rn(__fadd_rn(r[0], r[1]), __fadd_rn(r[2], r[3])),
                            __fadd_rn(__fadd_rn(r[4], r[5]), __fadd_rn(r[6], r[7])));
  }
  if (tid == 0)   ccount = 0;
  if (tid < 128)  tokbest[tid] = 0ull;
  __syncthreads();
  if (tid < 128) tnorm[tid] = fmaxf(__fsqrt_rn(__fadd_rn(pp[0][tid], pp[1][tid])), 1e-6f);
  __syncthreads();

  // ---- znT = flat_z_norm (token-major), written BEFORE the GEMM ----
  {
    const int tok = tid & 127, seg = tid >> 7;   // seg: 64-dim segment 0..3
    const float m = tnorm[tok];
    const float* zc = zb + tok;
    float* orow = znT + (size_t)(gtok0 + tok) * DIM + (seg << 6);
#pragma unroll 4
    for (int k4 = 0; k4 < 16; ++k4) {
      float4 o;
      o.x = __fdiv_rn(zc[(size_t)((seg << 6) + (k4 << 2) + 0) * TLEN], m);
      o.y = __fdiv_rn(zc[(size_t)((seg << 6) + (k4 << 2) + 1) * TLEN], m);
      o.z = __fdiv_rn(zc[(size_t)((seg << 6) + (k4 << 2) + 2) * TLEN], m);
      o.w = __fdiv_rn(zc[(size_t)((seg << 6) + (k4 << 2) + 3) * TLEN], m);
      *reinterpret_cast<float4*>(&orow[k4 << 2]) = o;
    }
  }

  // ---- A-fragments: raw z -> bf16 in registers (64 VGPR) ----
  bf16x8 afr[2][8];
  {
    const int tloc = (wr << 5) + (lane & 15);
    const int dr   = (lane >> 4) << 3;
#pragma unroll
    for (int i = 0; i < 2; ++i) {
      const float* zc = zb + tloc + (i << 4);
#pragma unroll
      for (int kb = 0; kb < 8; ++kb) {
        union { bf16x8 v; unsigned short u[8]; } a;
#pragma unroll
        for (int u = 0; u < 8; ++u)
          a.u[u] = f2bf(zc[(size_t)((kb << 5) + dr + u) * TLEN]);
        afr[i][kb] = a.v;
      }
    }
  }

  // window = 0.02*m_t per token handled by this lane (8 tokens: i x r)
  float wloc[2][4];
  {
    const int tb = (wr << 5) + ((lane >> 4) << 2);
#pragma unroll
    for (int i = 0; i < 2; ++i)
#pragma unroll
      for (int r = 0; r < 4; ++r) wloc[i][r] = 0.02f * tnorm[tb + (i << 4) + r];
  }

  const bool lc0 = (wc == 0) && ((lane & 15) == 0);   // lane carrying code chunk*64+0

  // Stage phase ph (16KB half-chunk) into bstage[bufi]; wave wv stages frags wv, wv+8.
#define STAGE(bufi, ph) do {                                                   \
    const char* gs_ = (const char*)wimg + ((size_t)(ph) << 14) + (wv << 10) + (lane << 4); \
    char* ls_ = &bstage[bufi][wv << 10];                                       \
    gl_lds16(gs_, ls_);                                                        \
    gl_lds16(gs_ + 8192, ls_ + 8192);                                          \
  } while (0)

  // Accumulate half hh (kb 4hh..4hh+3) from bstage[bufi] into acc.
#define CHALF(bufi, hh) do {                                                   \
    const char* lb_ = &bstage[bufi][(wc << 11) + (lane << 4)];                 \
    _Pragma("unroll")                                                          \
    for (int kb_ = 0; kb_ < 4; ++kb_) {                                        \
      const bf16x8 b0_ = *reinterpret_cast<const bf16x8*>(lb_ + (kb_ << 12));  \
      const bf16x8 b1_ = *reinterpret_cast<const bf16x8*>(lb_ + (kb_ << 12) + 1024); \
      const int kg_ = ((hh) << 2) + kb_;                                       \
      acc[0][0] = mfma16(afr[0][kg_], b0_, acc[0][0]);                         \
      acc[1][0] = mfma16(afr[1][kg_], b0_, acc[1][0]);                         \
      acc[0][1] = mfma16(afr[0][kg_], b1_, acc[0][1]);                         \
      acc[1][1] = mfma16(afr[1][kg_], b1_, acc[1][1]);                         \
    }                                                                          \
  } while (0)

#define ZEROACC() do {                                                         \
    _Pragma("unroll") for (int i_ = 0; i_ < 2; ++i_)                           \
    _Pragma("unroll") for (int j_ = 0; j_ < 2; ++j_)                           \
      acc[i_][j_] = (f32x4){0.f, 0.f, 0.f, 0.f};                               \
  } while (0)

  // running-max update + (optional) threshold collect — certified superset.
#define PROCESS(ch, DOC) do {                                                  \
    if ((ch) == 0 && lc0) {                                                    \
      _Pragma("unroll") for (int i_ = 0; i_ < 2; ++i_)                         \
      _Pragma("unroll") for (int r_ = 0; r_ < 4; ++r_)                         \
        acc[i_][0][r_] = -INFINITY;                                            \
    }                                                                          \
    _Pragma("unroll")                                                          \
    for (int i_ = 0; i_ < 2; ++i_) {                                           \
      _Pragma("unroll")                                                        \
      for (int r_ = 0; r_ < 4; ++r_) {                                         \
        float m_ = fmaxf(acc[i_][0][r_], acc[i_][1][r_]);                      \
        m_ = dppmax16(m_);                                                     \
        v1loc[i_][r_] = fmaxf(v1loc[i_][r_], m_);                              \
        if (DOC) {                                                             \
          const float t_ = v1loc[i_][r_] - wloc[i_][r_];                       \
          _Pragma("unroll")                                                    \
          for (int j_ = 0; j_ < 2; ++j_) {                                     \
            if (acc[i_][j_][r_] >= t_) {                                       \
              const int c_ = ((ch) << 6) + (wc << 5) + (j_ << 4) + (lane & 15); \
              if (c_ != 0) {                                                   \
                const int pos_ = atomicAdd(&ccount, 1);                        \
                if (pos_ < CAP)                                                \
                  clist[pos_] = (c_ << 7) | ((wr << 5) + (i_ << 4) + ((lane >> 4) << 2) + r_); \
              }                                                                \
            }                                                                  \
          }                                                                    \
        }                                                                      \
      }                                                                        \
    }                                                                          \
  } while (0)

  float v1loc[2][4];
#pragma unroll
  for (int i = 0; i < 2; ++i)
#pragma unroll
    for (int r = 0; r < 4; ++r) v1loc[i][r] = -INFINITY;
  f32x4 acc[2][2];

  // ---- warm-start: chunk 63 (phases 126,127), runmax only, no collect ----
  STAGE(0, 126);
  STAGE(1, 127);
  __syncthreads();                 // drains each wave's DMA; all staging visible
  ZEROACC();
  CHALF(0, 0);
  CHALF(1, 1);
  PROCESS(63, 0);
  __syncthreads();                 // all warmup reads done before buf0 restage
  STAGE(0, 0);

  // ---- main loop: 128 phases, dbuf, 1 barrier/phase ----
#pragma unroll 1
  for (int p = 0; p < 128; ++p) {
    __syncthreads();               // pre-barrier drain => STAGE(p) complete for all
    if (p + 1 < 128) STAGE((p + 1) & 1, p + 1);   // async; flies under compute
    if ((p & 1) == 0) ZEROACC();
    CHALF(p & 1, p & 1);
    if (p & 1) PROCESS(p >> 1, 1);
  }
#undef STAGE
#undef CHALF
#undef ZEROACC
#undef PROCESS
  __syncthreads();

  // ---- exact numpy-fp32 seq-FMA rescore + atomicMax64 verdict ----
  const int ncand = min(ccount, CAP);
  for (int e = tid; e < ncand; e += 512) {
    const int pk = clist[e];
    const int tloc = pk & 127;
    const int c = pk >> 7;
    const float* za = znT + (size_t)(gtok0 + tloc) * DIM;
    const float* wa = wnf32 + (size_t)c * DIM;
    float s = 0.f;
#pragma unroll 8
    for (int d = 0; d < DIM; ++d)
      s = fmaf(za[d], wa[d], s);
    unsigned uk = __float_as_uint(s);
    uk = (uk & 0x80000000u) ? ~uk : (uk | 0x80000000u);
    atomicMax(&tokbest[tloc],
              ((unsigned long long)uk << 32) | (unsigned)(4095 - c));
  }
  __syncthreads();

  // ---- decode per-token winner ----
  if (tid < 128) {
    const unsigned long long key = tokbest[tid];
    const int bc = 4095 - (int)(key & 0xFFFull);
    fidx[tid] = bc;
    out_codes[gtok0 + tid] = (float)bc;
    atomicAdd(&counts[bc], 1.0f);
  }
  __syncthreads();

  // ---- loss phase: sum (weight[idx] - raw z)^2 ----
  {
    float lpart = 0.f;
#pragma unroll 4
    for (int r = 0; r < 16; ++r) {
      const int tk = (r << 3) + wv;           // one token per wave per round
      const int code = fidx[tk];
      const float* zc = zb + tk;
      const float4 w4 = *reinterpret_cast<const float4*>(
          weight + (size_t)code * DIM + (lane << 2));   // coalesced row read
      float4 zr4;
      zr4.x = zc[(size_t)((lane << 2) + 0) * TLEN];     // scattered, L2-hot
      zr4.y = zc[(size_t)((lane << 2) + 1) * TLEN];
      zr4.z = zc[(size_t)((lane << 2) + 2) * TLEN];
      zr4.w = zc[(size_t)((lane << 2) + 3) * TLEN];
      const float dx = w4.x - zr4.x, dy = w4.y - zr4.y;
      const float dz = w4.z - zr4.z, dw_ = w4.w - zr4.w;
      lpart = fmaf(dx, dx, lpart); lpart = fmaf(dy, dy, lpart);
      lpart = fmaf(dz, dz, lpart); lpart = fmaf(dw_, dw_, lpart);
    }
#pragma unroll
    for (int off = 32; off; off >>= 1) lpart += __shfl_down(lpart, off, 64);
    if (lane == 0) atomicAdd(loss_accum, lpart);
  }
}

// ---------------- K3: new_cs, n, loss scalar + exclusive scan of counts ----------------
__global__ __launch_bounds__(256) void finalize_cs_kernel(
    const float* __restrict__ counts, const float* __restrict__ ema_cs,
    float* __restrict__ out_ncs, float* __restrict__ ws_n,
    const float* __restrict__ loss_accum, float* __restrict__ out_loss,
    int* __restrict__ offsets) {
  __shared__ float redf[4];
  __shared__ int   redi[4];
  const int tid = threadIdx.x;
  const int lane = tid & 63, wv = tid >> 6;
  const int base = tid << 4;
  int cloc[16]; int csum = 0; float fsum = 0.f;
#pragma unroll
  for (int j = 0; j < 16; ++j) {
    const int k = base + j;
    const float cf = counts[k];
    const float v = (k == 0) ? 0.f : 0.99f * ema_cs[k] + 0.01f * cf;
    out_ncs[k] = v; fsum += v;
    cloc[j] = csum; csum += (int)cf;
  }
  int inc = csum;                    // wave-inclusive scan
#pragma unroll
  for (int off = 1; off < 64; off <<= 1) {
    const int t = __shfl_up(inc, off, 64);
    if (lane >= off) inc += t;
  }
  float fs = fsum;
#pragma unroll
  for (int off = 32; off; off >>= 1) fs += __shfl_down(fs, off, 64);
  if (lane == 63) redi[wv] = inc;
  if (lane == 0)  redf[wv] = fs;
  __syncthreads();
  int wbase = 0;
#pragma unroll
  for (int w = 0; w < 4; ++w) wbase += (w < wv) ? redi[w] : 0;
  const int tbase = wbase + inc - csum;   // exclusive base for this thread
#pragma unroll
  for (int j = 0; j < 16; ++j) offsets[base + j] = tbase + cloc[j];
  if (tid == 0) {
    ws_n[0] = redf[0] + redf[1] + redf[2] + redf[3];
    out_loss[0] = 0.25f * loss_accum[0] / 16777216.0f;
  }
}

// ---------------- K3b: scatter token ids into per-code buckets ----------------
__global__ __launch_bounds__(256) void scatter_kernel(
    const float* __restrict__ codes, const int* __restrict__ offsets,
    int* __restrict__ cursor, int* __restrict__ bucket) {
  const int g = blockIdx.x * 256 + threadIdx.x;
  const int c = (int)codes[g];
  const int pos = atomicAdd(&cursor[c], 1);
  bucket[offsets[c] + pos] = g;
}

// ---------------- K3c: dw[k] = sum of znT rows in bucket k (4-batched gathers) ----------------
__global__ __launch_bounds__(256) void dw_kernel(
    const float* __restrict__ znT, const float* __restrict__ counts,
    const int* __restrict__ offsets, const int* __restrict__ bucket,
    float* __restrict__ dw) {
  const int c = blockIdx.x;
  const int cnt = (int)counts[c];
  const int off = offsets[c];
  const int tid = threadIdx.x;
  float acc = 0.f;
  int i = 0;
  for (; i + 4 <= cnt; i += 4) {          // batch 4 independent gathers per step
    const int g0 = bucket[off + i + 0];
    const int g1 = bucket[off + i + 1];
    const int g2 = bucket[off + i + 2];
    const int g3 = bucket[off + i + 3];
    const float a0 = znT[(size_t)g0 * DIM + tid];
    const float a1 = znT[(size_t)g1 * DIM + tid];
    const float a2 = znT[(size_t)g2 * DIM + tid];
    const float a3 = znT[(size_t)g3 * DIM + tid];
    acc += a0 + a1 + a2 + a3;
  }
  for (; i < cnt; ++i)
    acc += znT[(size_t)bucket[off + i] * DIM + tid];
  dw[(size_t)c * DIM + tid] = acc;        // writes every row (overwrites wnf32)
}

// ---------------- K4: new_ema_w (in place over dw) + new_weight ----------------
__global__ __launch_bounds__(256) void finalize_w_kernel(
    const float* __restrict__ ema_w, const float* __restrict__ ncs,
    const float* __restrict__ ws_n, float* __restrict__ new_ema_w,
    float* __restrict__ new_weight) {
  const int wid  = threadIdx.x >> 6;
  const int lane = threadIdx.x & 63;
  const int k    = (blockIdx.x << 2) + wid;
  const float n  = ws_n[0];
  const float cs = (ncs[k] + 1e-5f) / (n + 4096.0f * 1e-5f) * n;
  const float* erow = ema_w + k * DIM;
  float* nrow = new_ema_w + k * DIM;
  float* wrow = new_weight + k * DIM;
  const int d0 = lane << 2;
  float u[4]; float ss = 0.f;
#pragma unroll
  for (int j = 0; j < 4; ++j) {
    const float dwv = nrow[d0 + j];
    const float val = (k == 0) ? 0.f : 0.99f * erow[d0 + j] + 0.01f * dwv;
    nrow[d0 + j] = val;
    const float uu = val / cs;
    u[j] = uu;
    ss = fmaf(uu, uu, ss);
  }
#pragma unroll
  for (int off = 32; off; off >>= 1) ss += __shfl_xor(ss, off, 64);
  const float m = fmaxf(sqrtf(ss), 1e-6f);
#pragma unroll
  for (int j = 0; j < 4; ++j) wrow[d0 + j] = u[j] / m;
}

// ---------------- K5: final quantized = weight[idx], overwrites znT region ----------------
__global__ __launch_bounds__(256) void qwrite_kernel(
    const float* __restrict__ codes, const float* __restrict__ weight,
    float* __restrict__ out_q) {
  const int bb = blockIdx.x >> 4;
  const int t0 = (blockIdx.x & 15) << 6;
  const int ln = threadIdx.x & 63, qv = threadIdx.x >> 6;
  const int code = (int)codes[bb * TLEN + t0 + ln];
  const float* wrow = weight + (size_t)code * DIM;
  float* qb = out_q + (size_t)bb * DT + t0 + ln;
#pragma unroll 4
  for (int dd = 0; dd < 64; ++dd) {
    const int d = (qv << 6) + dd;
    qb[(size_t)d * TLEN] = wrow[d];        // gather L2-hot, store coalesced
  }
}

extern "C" void kernel_launch(void* const* d_in, const int* in_sizes, int n_in,
                              void* d_out, int out_size, void* d_ws, size_t ws_size,
                              hipStream_t stream) {
  const float* z      = (const float*)d_in[0];   // [64,256,1024]
  const float* weight = (const float*)d_in[1];   // [4096,256]
  const float* ema_cs = (const float*)d_in[2];   // [4096]
  const float* ema_w  = (const float*)d_in[3];   // [4096,256]

  float* out = (float*)d_out;
  // output layout (floats): quantized | loss | codes | new_weight | new_cs | new_ema_w
  float* out_q     = out;                    // 16777216 (holds znT until qwrite)
  float* out_loss  = out + 16777216;         // 1
  float* out_codes = out + 16777217;         // 65536
  float* out_nw    = out + 16842753;         // 1048576 (temp: wimg/bucket/offsets/cursor)
  float* out_ncs   = out + 17891329;         // 4096
  float* out_new   = out + 17895425;         // 1048576 (wnf32 -> dw, overwritten in order)

  float* counts     = (float*)d_ws;          // 4096 floats
  float* loss_accum = counts + 4096;         // 1
  float* ws_n       = counts + 4097;         // 1
  float* wnorms     = counts + 4352;         // 4096 floats, 16B-aligned

  // Scratch aliased into dead d_out regions:
  // wimg: 2 MiB bf16 image at out_nw+3 (16B-aligned); dead after vq_main.
  // bucket overlays the dead image; offsets/cursor sit past it.
  // wnf32 = out_new region; dead after vq_main, then overwritten by dw_kernel.
  unsigned short* wimg = (unsigned short*)(out_nw + 3);
  int* bucket  = (int*)(out_nw + 3);         // 65536 ints (aliases dead wimg)
  int* offsets = (int*)(out_nw + 524292);    // 4096 ints
  int* cursor  = (int*)(out_nw + 528388);    // 4096 ints
  float* wnf32 = out_new;

  hipMemsetAsync(d_ws, 0, 4098 * sizeof(float), stream);
  hipMemsetAsync(cursor, 0, 4096 * sizeof(int), stream);

  wnorm_kernel<<<16, 256, 0, stream>>>(weight, wnorms);
  wnf32_kernel<<<1024, 256, 0, stream>>>(weight, wnorms, wnf32);
  wfrag_kernel<<<512, 256, 0, stream>>>(wnf32, wimg);
  vq_main_kernel<<<512, 512, 0, stream>>>(z, weight, wimg, wnf32, out_q /*znT*/,
                                          out_codes, counts, loss_accum);
  finalize_cs_kernel<<<1, 256, 0, stream>>>(counts, ema_cs, out_ncs, ws_n,
                                            loss_accum, out_loss, offsets);
  scatter_kernel<<<256, 256, 0, stream>>>(out_codes, offsets, cursor, bucket);
  dw_kernel<<<NUM_K, 256, 0, stream>>>(out_q /*znT*/, counts, offsets, bucket, out_new);
  finalize_w_kernel<<<NUM_K / 4, 256, 0, stream>>>(ema_w, out_ncs, ws_n,
                                                   out_new, out_nw);
  qwrite_kernel<<<1024, 256, 0, stream>>>(out_codes, weight, out_q);
}